// Round 3
// baseline (265.988 us; speedup 1.0000x reference)
//
#include <hip/hip_runtime.h>
#include <stdint.h>

typedef unsigned int u32;
typedef unsigned long long u64;

#define SCORE_THR 0.05f
#define NMS_THR   0.5f
#define TK        2048
#define CAP       4096
#define BASE14    ((int)(0x3D4CCCCDu >> 14))   // (bits of 0.05f) >> 14 = 62771

// ---------------- ws layout (bytes) ----------------
// 0      : hist/offs u32[4096]  (zeroed; k_scan rewrites in-place as suffix offsets)
// 16384  : binpos    u32[4096]  (zeroed)
// 32768  : hdr       u32[64]    (zeroed)  hdr[3]=pivot bin (local) hdr[5]=n>=pivot hdr[6]=total
// 33024  : cand_bx   f32[2048*4]
// 65792  : nms_bx    f32[2048*4]
// 98560  : vals      f32[2048]
// 106752 : mask      u32[2048*64] (512 KB); buf u64[4096] ALIASES mask base
//          (buf dead before k_mask writes every mask word)
// total 631040 B
#define WS_OFFS   0
#define WS_BINPOS 16384
#define WS_HDR    32768
#define WS_CBX    33024
#define WS_NBX    65792
#define WS_VALS   98560
#define WS_MASK   106752
#define WS_BUF    106752

// ---- single-pass histogram over key bits [30:14] (4096 bins) ----
__global__ void k_hist(const float* __restrict__ scores,
                       const float* __restrict__ center,
                       int R, u32* __restrict__ hist) {
    __shared__ u32 h[4096];
    for (int t = threadIdx.x; t < 4096; t += blockDim.x) h[t] = 0;
    __syncthreads();
    int stride = gridDim.x * blockDim.x;
    for (int r = blockIdx.x * blockDim.x + threadIdx.x; r < R; r += stride) {
        float cs = center[r];
        const float* srow = scores + (size_t)r * 11 + 1;
#pragma unroll
        for (int k = 0; k < 10; k++) {
            float s = __fmul_rn(srow[k], cs);
            if (s > SCORE_THR) {
                u32 key = __float_as_uint(s);
                int b = (int)(key >> 14) - BASE14;
                b = min(max(b, 0), 4095);
                atomicAdd(&h[b], 1u);
            }
        }
    }
    __syncthreads();
    for (int t = threadIdx.x; t < 4096; t += blockDim.x)
        if (h[t]) atomicAdd(&hist[t], h[t]);
}

// ---- scan: rewrite hist -> suffix offsets (count in strictly-higher bins),
//      find pivot bin containing the 2048th element (one wave) ----
__global__ void k_scan(u32* __restrict__ offs, u32* hdr) {
    int lane = threadIdx.x;             // 64 lanes x 64 bins
    int base = 4096 - 64 * (lane + 1);  // lane 0 = topmost segment
    u32 v[64];
    u32 segsum = 0;
#pragma unroll
    for (int j = 0; j < 64; j++) { v[j] = offs[base + j]; segsum += v[j]; }
    u32 incl = segsum;
    for (int off = 1; off < 64; off <<= 1) {
        u32 t = (u32)__shfl_up((int)incl, off);
        if (lane >= off) incl += t;
    }
    u32 excl = incl - segsum;           // elements in bins above my segment
    u32 total = (u32)__shfl((int)incl, 63);
    // in-place suffix offsets: offs[b] = #elements in bins > b
    u32 run = excl;
#pragma unroll
    for (int j = 63; j >= 0; j--) { offs[base + j] = run; run += v[j]; }
    if (lane == 0) hdr[6] = total;
    if (total < (u32)TK) {
        if (lane == 0) { hdr[3] = 0; hdr[5] = total; }   // take-all
        return;
    }
    bool cross = (excl < (u32)TK) && (incl >= (u32)TK);
    if (cross) {
        u32 cum = excl;
#pragma unroll
        for (int j = 63; j >= 0; j--) {
            u32 nc = cum + v[j];
            if (nc >= (u32)TK) { hdr[3] = (u32)(base + j); hdr[5] = nc; break; }
            cum = nc;
        }
    }
}

// ---- collect: bucket-scatter candidates at/above pivot bin to final slots ----
__global__ void k_collect(const float* __restrict__ scores,
                          const float* __restrict__ center,
                          int R, const u32* __restrict__ hdr,
                          const u32* __restrict__ offs, u32* __restrict__ binpos,
                          u64* __restrict__ buf) {
    u32 thr = hdr[3];
    int stride = gridDim.x * blockDim.x;
    for (int r = blockIdx.x * blockDim.x + threadIdx.x; r < R; r += stride) {
        float cs = center[r];
        const float* srow = scores + (size_t)r * 11 + 1;
#pragma unroll
        for (int k = 0; k < 10; k++) {
            float s = __fmul_rn(srow[k], cs);
            if (s > SCORE_THR) {
                u32 key = __float_as_uint(s);
                int b = (int)(key >> 14) - BASE14;
                b = min(max(b, 0), 4095);
                if ((u32)b >= thr) {
                    u32 slot = atomicAdd(&binpos[b], 1u);
                    u32 pos = offs[b] + slot;
                    if (pos < CAP) {
                        u32 idx = (u32)r * 10u + (u32)k;
                        buf[pos] = ((u64)key << 32) | (u64)(~idx);
                    }
                }
            }
        }
    }
}

// ---- gather rank t: binary-search bin, select k-th largest within tiny run,
//      then clip box / build NMS box / write vals ----
__global__ void k_gather(const float* __restrict__ boxes,
                         const u32* __restrict__ offs, const u32* __restrict__ hdr,
                         const u64* __restrict__ buf, float* __restrict__ cand_bx,
                         float* __restrict__ nms_bx, float* __restrict__ vals) {
    int t = blockIdx.x * blockDim.x + threadIdx.x;
    if (t >= TK) return;
    u32 n = hdr[5]; if (n > (u32)TK) n = TK;
    u64 v = 0;
    if ((u32)t < n) {
        // smallest b with offs[b] <= t  (offs non-increasing in b)
        int lo = 0, hi = 4095;
        while (lo < hi) {
            int mid = (lo + hi) >> 1;
            if (offs[mid] <= (u32)t) hi = mid; else lo = mid + 1;
        }
        int b = lo;
        u32 start = offs[b];
        u32 above = (b > 0) ? offs[b - 1] : hdr[6];
        u32 end = above; if (end > (u32)CAP) end = CAP;
        u32 k = (u32)t - start;
        for (u32 i = start; i < end; i++) {
            u64 x = buf[i];
            u32 rk = 0;
            for (u32 j2 = start; j2 < end; j2++) rk += (buf[j2] > x) ? 1u : 0u;
            if (rk == k) { v = x; break; }
        }
    }
    u32 key = (u32)(v >> 32);
    float c0 = 0.f, c1 = 0.f, c2 = 0.f, c3 = 0.f;
    float n0 = 0.f, n1 = 0.f, n2 = 0.f, n3 = 0.f;
    float val = -1.0f;
    if (key != 0) {
        u32 idx = ~(u32)v;
        u32 r = idx / 10u, cls = idx % 10u;
        const float* bp = boxes + (size_t)r * 4;
        c0 = fminf(fmaxf(bp[0], 0.f), 1920.f);
        c1 = fminf(fmaxf(bp[1], 0.f), 1080.f);
        c2 = fminf(fmaxf(bp[2], 0.f), 1920.f);
        c3 = fminf(fmaxf(bp[3], 0.f), 1080.f);
        float offv = __fmul_rn((float)cls, 3001.0f);  // exact: small ints
        n0 = __fadd_rn(c0, offv); n1 = __fadd_rn(c1, offv);
        n2 = __fadd_rn(c2, offv); n3 = __fadd_rn(c3, offv);
        val = __uint_as_float(key);
    } else {
        val = 0.0f;  // padding: below SCORE_THR, never kept
    }
    cand_bx[t * 4 + 0] = c0; cand_bx[t * 4 + 1] = c1;
    cand_bx[t * 4 + 2] = c2; cand_bx[t * 4 + 3] = c3;
    nms_bx[t * 4 + 0] = n0; nms_bx[t * 4 + 1] = n1;
    nms_bx[t * 4 + 2] = n2; nms_bx[t * 4 + 3] = n3;
    vals[t] = val;
}

// ---- suppression bitmask: mask[row][word] over 2048x2048 pairs ----
__global__ void k_mask(const float* __restrict__ nms_bx, u32* __restrict__ mask) {
    __shared__ float4 cb[64];
    __shared__ float ca[64];
    int tid = threadIdx.x;
    int colbase = blockIdx.x * 64, rowbase = blockIdx.y * 64;
    float4 c = ((const float4*)nms_bx)[colbase + tid];
    cb[tid] = c;
    ca[tid] = __fmul_rn(fmaxf(__fsub_rn(c.z, c.x), 0.f),
                        fmaxf(__fsub_rn(c.w, c.y), 0.f));
    int row = rowbase + tid;
    float4 rb = ((const float4*)nms_bx)[row];
    float rarea = __fmul_rn(fmaxf(__fsub_rn(rb.z, rb.x), 0.f),
                            fmaxf(__fsub_rn(rb.w, rb.y), 0.f));
    __syncthreads();
    u32 w0 = 0, w1 = 0;
    for (int cc = 0; cc < 64; cc++) {
        int col = colbase + cc;
        if (col > row) {
            float4 cbv = cb[cc];
            float ltx = fmaxf(rb.x, cbv.x), lty = fmaxf(rb.y, cbv.y);
            float rbx = fminf(rb.z, cbv.z), rby = fminf(rb.w, cbv.w);
            float w = fmaxf(__fsub_rn(rbx, ltx), 0.f);
            float h = fmaxf(__fsub_rn(rby, lty), 0.f);
            float inter = __fmul_rn(w, h);
            // ref order: ((area_i + area_j) - inter) + 1e-9
            float denom = __fadd_rn(__fsub_rn(__fadd_rn(rarea, ca[cc]), inter), 1e-9f);
            float iou = __fdiv_rn(inter, denom);
            if (iou > NMS_THR) {
                if (cc < 32) w0 |= 1u << cc; else w1 |= 1u << (cc - 32);
            }
        }
    }
    mask[row * 64 + blockIdx.x * 2 + 0] = w0;
    mask[row * 64 + blockIdx.x * 2 + 1] = w1;
}

// ---- greedy scan: word-parallel (64 broadcasts total) + output write ----
__global__ void k_final(const u32* __restrict__ mask, const float* __restrict__ vals,
                        const float* __restrict__ cand_bx, float* __restrict__ out) {
    int lane = threadIdx.x;  // lane owns keep/removed bits [lane*32, lane*32+32)
    u32 validw = 0;
#pragma unroll
    for (int b = 0; b < 32; b++)
        validw |= (vals[lane * 32 + b] > SCORE_THR ? 1u : 0u) << b;
    u32 removed = 0, keepw = 0;
    u32 bufA[32], bufB[32];
#pragma unroll
    for (int j = 0; j < 32; j++) bufA[j] = mask[j * 64 + lane];
    for (int w = 0; w < 64; w += 2) {
#pragma unroll
        for (int j = 0; j < 32; j++) bufB[j] = mask[((w + 1) * 32 + j) * 64 + lane];
        {
            u32 alive = validw & ~removed;
#pragma unroll
            for (int j = 0; j < 32; j++)
                alive &= ((alive >> j) & 1u) ? ~bufA[j] : 0xFFFFFFFFu;
            u32 kw = (u32)__shfl((int)alive, w);
            if (lane == w) keepw = kw;
            u32 acc = 0;
#pragma unroll
            for (int j = 0; j < 32; j++) acc |= ((kw >> j) & 1u) ? bufA[j] : 0u;
            removed |= acc;
        }
        if (w + 2 < 64) {
#pragma unroll
            for (int j = 0; j < 32; j++) bufA[j] = mask[((w + 2) * 32 + j) * 64 + lane];
        }
        {
            u32 alive = validw & ~removed;
#pragma unroll
            for (int j = 0; j < 32; j++)
                alive &= ((alive >> j) & 1u) ? ~bufB[j] : 0xFFFFFFFFu;
            u32 kw = (u32)__shfl((int)alive, w + 1);
            if (lane == w + 1) keepw = kw;
            u32 acc = 0;
#pragma unroll
            for (int j = 0; j < 32; j++) acc |= ((kw >> j) & 1u) ? bufB[j] : 0u;
            removed |= acc;
        }
    }
#pragma unroll
    for (int b = 0; b < 32; b++) {
        int i = lane * 32 + b;
        bool kp = (keepw >> b) & 1u;
        const float4 bx = ((const float4*)cand_bx)[i];
        out[i * 5 + 0] = kp ? bx.x : 0.f;
        out[i * 5 + 1] = kp ? bx.y : 0.f;
        out[i * 5 + 2] = kp ? bx.z : 0.f;
        out[i * 5 + 3] = kp ? bx.w : 0.f;
        out[i * 5 + 4] = kp ? vals[i] : 0.f;
    }
}

extern "C" void kernel_launch(void* const* d_in, const int* in_sizes, int n_in,
                              void* d_out, int out_size, void* d_ws, size_t ws_size,
                              hipStream_t stream) {
    const float* boxes = (const float*)d_in[0];
    const float* scores = (const float*)d_in[1];
    const float* center = (const float*)d_in[2];
    float* out = (float*)d_out;
    int R = in_sizes[2];

    char* w = (char*)d_ws;
    u32* offs   = (u32*)(w + WS_OFFS);
    u32* binpos = (u32*)(w + WS_BINPOS);
    u32* hdr    = (u32*)(w + WS_HDR);
    float* cbx  = (float*)(w + WS_CBX);
    float* nbx  = (float*)(w + WS_NBX);
    float* vls  = (float*)(w + WS_VALS);
    u32* mask   = (u32*)(w + WS_MASK);
    u64* buf    = (u64*)(w + WS_BUF);   // aliases mask (disjoint lifetime)

    // ws is poisoned 0xAA before every call: zero hist + binpos + hdr
    hipMemsetAsync(w, 0, WS_CBX, stream);

    k_hist<<<1024, 256, 0, stream>>>(scores, center, R, offs);
    k_scan<<<1, 64, 0, stream>>>(offs, hdr);
    k_collect<<<1024, 256, 0, stream>>>(scores, center, R, hdr, offs, binpos, buf);
    k_gather<<<8, 256, 0, stream>>>(boxes, offs, hdr, buf, cbx, nbx, vls);
    k_mask<<<dim3(32, 32), 64, 0, stream>>>(nbx, mask);
    k_final<<<1, 64, 0, stream>>>(mask, vls, cbx, out);
}

// Round 4
// 240.623 us; speedup vs baseline: 1.1054x; 1.1054x over previous
//
#include <hip/hip_runtime.h>
#include <stdint.h>

typedef unsigned int u32;
typedef unsigned long long u64;

#define SCORE_THR 0.05f
#define NMS_THR   0.5f
#define TK        2048
#define CAP       4096
#define BASE14    ((int)(0x3D4CCCCDu >> 14))   // (bits of 0.05f) >> 14 = 62771

// ---------------- ws layout (bytes) ----------------
// 0      : hist/offs u32[4096] (zeroed; last hist block rewrites as suffix offsets)
// 16384  : binpos    u32[4096] (zeroed)
// 32768  : hdr       u32[64]   (zeroed) hdr[3]=pivot bin hdr[5]=n>=pivot hdr[6]=total hdr[7]=ticket
// 33024  : cand_bx   f32[2048*4] (zeroed: padding slots)
// 65792  : nms_bx    f32[2048*4] (zeroed)
// 98560  : vals      f32[2048]   (zeroed)
// 106752 : mask      u32[2048*64] (512 KB); buf u64[4096] ALIASES mask base
//          (buf dead after k_rank, before k_mask writes every mask word)
#define WS_OFFS   0
#define WS_BINPOS 16384
#define WS_HDR    32768
#define WS_CBX    33024
#define WS_NBX    65792
#define WS_VALS   98560
#define WS_MASK   106752
#define WS_BUF    106752

// ---- histogram over key bits [30:14] (4096 bins) + fused last-block scan ----
__global__ void k_hist(const float* __restrict__ scores,
                       const float* __restrict__ center,
                       int R, u32* __restrict__ hist, u32* __restrict__ hdr) {
    __shared__ u32 h[4096];
    __shared__ u32 lastblk;
    for (int t = threadIdx.x; t < 4096; t += blockDim.x) h[t] = 0;
    __syncthreads();
    int stride = gridDim.x * blockDim.x;
    for (int r = blockIdx.x * blockDim.x + threadIdx.x; r < R; r += stride) {
        float cs = center[r];
        const float* srow = scores + (size_t)r * 11 + 1;
#pragma unroll
        for (int k = 0; k < 10; k++) {
            float s = __fmul_rn(srow[k], cs);
            if (s > SCORE_THR) {
                u32 key = __float_as_uint(s);
                int b = (int)(key >> 14) - BASE14;
                b = min(max(b, 0), 4095);
                atomicAdd(&h[b], 1u);
            }
        }
    }
    __syncthreads();
    for (int t = threadIdx.x; t < 4096; t += blockDim.x)
        if (h[t]) atomicAdd(&hist[t], h[t]);
    // ---- last-block-standing does the scan (atomic handshake: device-coherent) ----
    __threadfence();
    __syncthreads();
    if (threadIdx.x == 0) lastblk = atomicAdd(&hdr[7], 1u);
    __syncthreads();
    if (lastblk != gridDim.x - 1) return;
    if (threadIdx.x >= 64) return;
    int lane = threadIdx.x;             // one wave: 64 lanes x 64 bins
    int base = 4096 - 64 * (lane + 1);  // lane 0 = topmost segment
    u32 v[64];
    u32 segsum = 0;
#pragma unroll
    for (int j = 0; j < 64; j++) { v[j] = atomicAdd(&hist[base + j], 0u); segsum += v[j]; }
    u32 incl = segsum;
    for (int off = 1; off < 64; off <<= 1) {
        u32 t = (u32)__shfl_up((int)incl, off);
        if (lane >= off) incl += t;
    }
    u32 excl = incl - segsum;           // elements in bins above my segment
    u32 total = (u32)__shfl((int)incl, 63);
    // in-place suffix offsets: hist[b] := #elements in bins > b
    u32 run = excl;
#pragma unroll
    for (int j = 63; j >= 0; j--) { hist[base + j] = run; run += v[j]; }
    if (lane == 0) hdr[6] = total;
    if (total < (u32)TK) {
        if (lane == 0) { hdr[3] = 0; hdr[5] = total; }   // take-all
        return;
    }
    if ((excl < (u32)TK) && (incl >= (u32)TK)) {
        u32 cum = excl;
#pragma unroll
        for (int j = 63; j >= 0; j--) {
            u32 nc = cum + v[j];
            if (nc >= (u32)TK) { hdr[3] = (u32)(base + j); hdr[5] = nc; break; }
            cum = nc;
        }
    }
}

// ---- collect: bucket-scatter candidates at/above pivot bin (bin-grouped) ----
__global__ void k_collect(const float* __restrict__ scores,
                          const float* __restrict__ center,
                          int R, const u32* __restrict__ hdr,
                          const u32* __restrict__ offs, u32* __restrict__ binpos,
                          u64* __restrict__ buf) {
    u32 thr = hdr[3];
    int stride = gridDim.x * blockDim.x;
    for (int r = blockIdx.x * blockDim.x + threadIdx.x; r < R; r += stride) {
        float cs = center[r];
        const float* srow = scores + (size_t)r * 11 + 1;
#pragma unroll
        for (int k = 0; k < 10; k++) {
            float s = __fmul_rn(srow[k], cs);
            if (s > SCORE_THR) {
                u32 key = __float_as_uint(s);
                int b = (int)(key >> 14) - BASE14;
                b = min(max(b, 0), 4095);
                if ((u32)b >= thr) {
                    u32 slot = atomicAdd(&binpos[b], 1u);
                    u32 pos = offs[b] + slot;
                    if (pos < CAP) {
                        u32 idx = (u32)r * 10u + (u32)k;
                        buf[pos] = ((u64)key << 32) | (u64)(~idx);
                    }
                }
            }
        }
    }
}

// ---- per-ELEMENT rank (LDS-staged, O(run) per element) + scatter-write ----
__global__ __launch_bounds__(1024) void k_rank(
        const float* __restrict__ boxes, const u32* __restrict__ offs,
        const u32* __restrict__ hdr, const u64* __restrict__ buf,
        float* __restrict__ cand_bx, float* __restrict__ nms_bx,
        float* __restrict__ vals) {
    __shared__ u64 kb[CAP];
    __shared__ u32 lo[4096];
    int tid = threadIdx.x;
    u32 n = hdr[5]; if (n > (u32)CAP) n = CAP;
    u32 total = hdr[6];
    for (int t = tid; t < CAP; t += 1024) kb[t] = (t < (int)n) ? buf[t] : 0ull;
    for (int t = tid; t < 4096; t += 1024) lo[t] = offs[t];
    __syncthreads();
    for (int i = tid; i < (int)n; i += 1024) {
        u64 x = kb[i];
        u32 key = (u32)(x >> 32);
        int b = (int)(key >> 14) - BASE14;
        b = min(max(b, 0), 4095);
        u32 start = lo[b];
        u32 end = (b > 0) ? lo[b - 1] : total;
        if (end > (u32)CAP) end = CAP;
        u32 rk = start;                 // global rank = bin start + within-bin rank
        for (u32 j = start; j < end; j++) rk += (kb[j] > x) ? 1u : 0u;
        if (rk < (u32)TK) {
            u32 idx = ~(u32)x;
            u32 r = idx / 10u, cls = idx % 10u;
            const float* bp = boxes + (size_t)r * 4;
            float c0 = fminf(fmaxf(bp[0], 0.f), 1920.f);
            float c1 = fminf(fmaxf(bp[1], 0.f), 1080.f);
            float c2 = fminf(fmaxf(bp[2], 0.f), 1920.f);
            float c3 = fminf(fmaxf(bp[3], 0.f), 1080.f);
            float offv = __fmul_rn((float)cls, 3001.0f);  // exact: small ints
            cand_bx[rk * 4 + 0] = c0; cand_bx[rk * 4 + 1] = c1;
            cand_bx[rk * 4 + 2] = c2; cand_bx[rk * 4 + 3] = c3;
            nms_bx[rk * 4 + 0] = __fadd_rn(c0, offv);
            nms_bx[rk * 4 + 1] = __fadd_rn(c1, offv);
            nms_bx[rk * 4 + 2] = __fadd_rn(c2, offv);
            nms_bx[rk * 4 + 3] = __fadd_rn(c3, offv);
            vals[rk] = __uint_as_float(key);
        }
    }
}

// ---- suppression bitmask: mask[row][word] over 2048x2048 pairs ----
__global__ void k_mask(const float* __restrict__ nms_bx, u32* __restrict__ mask) {
    __shared__ float4 cb[64];
    __shared__ float ca[64];
    int tid = threadIdx.x;
    int colbase = blockIdx.x * 64, rowbase = blockIdx.y * 64;
    float4 c = ((const float4*)nms_bx)[colbase + tid];
    cb[tid] = c;
    ca[tid] = __fmul_rn(fmaxf(__fsub_rn(c.z, c.x), 0.f),
                        fmaxf(__fsub_rn(c.w, c.y), 0.f));
    int row = rowbase + tid;
    float4 rb = ((const float4*)nms_bx)[row];
    float rarea = __fmul_rn(fmaxf(__fsub_rn(rb.z, rb.x), 0.f),
                            fmaxf(__fsub_rn(rb.w, rb.y), 0.f));
    __syncthreads();
    u32 w0 = 0, w1 = 0;
    for (int cc = 0; cc < 64; cc++) {
        int col = colbase + cc;
        if (col > row) {
            float4 cbv = cb[cc];
            float ltx = fmaxf(rb.x, cbv.x), lty = fmaxf(rb.y, cbv.y);
            float rbx = fminf(rb.z, cbv.z), rby = fminf(rb.w, cbv.w);
            float w = fmaxf(__fsub_rn(rbx, ltx), 0.f);
            float h = fmaxf(__fsub_rn(rby, lty), 0.f);
            float inter = __fmul_rn(w, h);
            // ref order: ((area_i + area_j) - inter) + 1e-9
            float denom = __fadd_rn(__fsub_rn(__fadd_rn(rarea, ca[cc]), inter), 1e-9f);
            float iou = __fdiv_rn(inter, denom);
            if (iou > NMS_THR) {
                if (cc < 32) w0 |= 1u << cc; else w1 |= 1u << (cc - 32);
            }
        }
    }
    mask[row * 64 + blockIdx.x * 2 + 0] = w0;
    mask[row * 64 + blockIdx.x * 2 + 1] = w1;
}

// ---- greedy scan: word-parallel (64 broadcasts total) + output write ----
__global__ void k_final(const u32* __restrict__ mask, const float* __restrict__ vals,
                        const float* __restrict__ cand_bx, float* __restrict__ out) {
    int lane = threadIdx.x;  // lane owns keep/removed bits [lane*32, lane*32+32)
    u32 validw = 0;
#pragma unroll
    for (int b = 0; b < 32; b++)
        validw |= (vals[lane * 32 + b] > SCORE_THR ? 1u : 0u) << b;
    u32 removed = 0, keepw = 0;
    u32 bufA[32], bufB[32];
#pragma unroll
    for (int j = 0; j < 32; j++) bufA[j] = mask[j * 64 + lane];
    for (int w = 0; w < 64; w += 2) {
#pragma unroll
        for (int j = 0; j < 32; j++) bufB[j] = mask[((w + 1) * 32 + j) * 64 + lane];
        {
            u32 alive = validw & ~removed;
#pragma unroll
            for (int j = 0; j < 32; j++)
                alive &= ((alive >> j) & 1u) ? ~bufA[j] : 0xFFFFFFFFu;
            u32 kw = (u32)__shfl((int)alive, w);
            if (lane == w) keepw = kw;
            u32 acc = 0;
#pragma unroll
            for (int j = 0; j < 32; j++) acc |= ((kw >> j) & 1u) ? bufA[j] : 0u;
            removed |= acc;
        }
        if (w + 2 < 64) {
#pragma unroll
            for (int j = 0; j < 32; j++) bufA[j] = mask[((w + 2) * 32 + j) * 64 + lane];
        }
        {
            u32 alive = validw & ~removed;
#pragma unroll
            for (int j = 0; j < 32; j++)
                alive &= ((alive >> j) & 1u) ? ~bufB[j] : 0xFFFFFFFFu;
            u32 kw = (u32)__shfl((int)alive, w + 1);
            if (lane == w + 1) keepw = kw;
            u32 acc = 0;
#pragma unroll
            for (int j = 0; j < 32; j++) acc |= ((kw >> j) & 1u) ? bufB[j] : 0u;
            removed |= acc;
        }
    }
#pragma unroll
    for (int b = 0; b < 32; b++) {
        int i = lane * 32 + b;
        bool kp = (keepw >> b) & 1u;
        const float4 bx = ((const float4*)cand_bx)[i];
        out[i * 5 + 0] = kp ? bx.x : 0.f;
        out[i * 5 + 1] = kp ? bx.y : 0.f;
        out[i * 5 + 2] = kp ? bx.z : 0.f;
        out[i * 5 + 3] = kp ? bx.w : 0.f;
        out[i * 5 + 4] = kp ? vals[i] : 0.f;
    }
}

extern "C" void kernel_launch(void* const* d_in, const int* in_sizes, int n_in,
                              void* d_out, int out_size, void* d_ws, size_t ws_size,
                              hipStream_t stream) {
    const float* boxes = (const float*)d_in[0];
    const float* scores = (const float*)d_in[1];
    const float* center = (const float*)d_in[2];
    float* out = (float*)d_out;
    int R = in_sizes[2];

    char* w = (char*)d_ws;
    u32* offs   = (u32*)(w + WS_OFFS);
    u32* binpos = (u32*)(w + WS_BINPOS);
    u32* hdr    = (u32*)(w + WS_HDR);
    float* cbx  = (float*)(w + WS_CBX);
    float* nbx  = (float*)(w + WS_NBX);
    float* vls  = (float*)(w + WS_VALS);
    u32* mask   = (u32*)(w + WS_MASK);
    u64* buf    = (u64*)(w + WS_BUF);   // aliases mask (disjoint lifetime)

    // zero hist + binpos + hdr + cand/nms/vals padding (ws poisoned 0xAA per call)
    hipMemsetAsync(w, 0, WS_MASK, stream);

    k_hist<<<1024, 256, 0, stream>>>(scores, center, R, offs, hdr);
    k_collect<<<1024, 256, 0, stream>>>(scores, center, R, hdr, offs, binpos, buf);
    k_rank<<<1, 1024, 0, stream>>>(boxes, offs, hdr, buf, cbx, nbx, vls);
    k_mask<<<dim3(32, 32), 64, 0, stream>>>(nbx, mask);
    k_final<<<1, 64, 0, stream>>>(mask, vls, cbx, out);
}

// Round 5
// 230.634 us; speedup vs baseline: 1.1533x; 1.0433x over previous
//
#include <hip/hip_runtime.h>
#include <stdint.h>

typedef unsigned int u32;
typedef unsigned long long u64;

#define SCORE_THR 0.05f
#define NMS_THR   0.5f
#define TK        2048
#define CAP       4096
#define BASE14    ((int)(0x3D4CCCCDu >> 14))   // (bits of 0.05f) >> 14 = 62771
#define MAGIC11   3123612579ull                // ceil(2^35/11); exact /11 for e < 2^35

// ---------------- ws layout (bytes) ----------------
// 0      : hist/offs u32[4096] (zeroed; last hist block rewrites as suffix offsets)
// 16384  : binpos    u32[4096] (zeroed)
// 32768  : hdr       u32[64]   (zeroed) hdr[3]=pivot bin hdr[5]=n>=pivot hdr[6]=total hdr[7]=ticket
// 33024  : cand_bx   f32[2048*4] (zeroed: padding slots)
// 65792  : nms_bx    f32[2048*4] (zeroed)
// 98560  : vals      f32[2048]   (zeroed)
// 106752 : mask      u32[2048*64] (512 KB); buf u64[4096] ALIASES mask base
//          (buf dead after k_rank, before k_mask writes every mask word)
#define WS_OFFS   0
#define WS_BINPOS 16384
#define WS_HDR    32768
#define WS_CBX    33024
#define WS_NBX    65792
#define WS_VALS   98560
#define WS_MASK   106752
#define WS_BUF    106752

// ---- histogram over key bits [30:14] (4096 bins), coalesced float4 stream,
//      + fused last-block scan ----
__global__ void k_hist(const float* __restrict__ scores,
                       const float* __restrict__ center,
                       int R, u32* __restrict__ hist, u32* __restrict__ hdr) {
    __shared__ u32 h[4096];
    __shared__ u32 lastblk;
    for (int t = threadIdx.x; t < 4096; t += blockDim.x) h[t] = 0;
    __syncthreads();
    int total_e = R * 11;
    int nq = total_e >> 2;
    int stride = gridDim.x * blockDim.x;
    int tid0 = blockIdx.x * blockDim.x + threadIdx.x;
    for (int q = tid0; q < nq; q += stride) {
        float4 v4 = ((const float4*)scores)[q];
        int e = q << 2;
        float vv[4] = {v4.x, v4.y, v4.z, v4.w};
#pragma unroll
        for (int j = 0; j < 4; j++) {
            int e2 = e + j;
            u32 r = (u32)(((u64)(u32)e2 * MAGIC11) >> 35);
            u32 c = (u32)e2 - r * 11u;
            if (c != 0u) {
                float s = __fmul_rn(vv[j], center[r]);
                if (s > SCORE_THR) {
                    u32 key = __float_as_uint(s);
                    int b = (int)(key >> 14) - BASE14;
                    b = min(max(b, 0), 4095);
                    atomicAdd(&h[b], 1u);
                }
            }
        }
    }
    if (tid0 == 0) {                      // tail (total_e % 4)
        for (int e2 = nq << 2; e2 < total_e; e2++) {
            u32 r = (u32)(((u64)(u32)e2 * MAGIC11) >> 35);
            u32 c = (u32)e2 - r * 11u;
            if (c != 0u) {
                float s = __fmul_rn(scores[e2], center[r]);
                if (s > SCORE_THR) {
                    u32 key = __float_as_uint(s);
                    int b = (int)(key >> 14) - BASE14;
                    b = min(max(b, 0), 4095);
                    atomicAdd(&h[b], 1u);
                }
            }
        }
    }
    __syncthreads();
    for (int t = threadIdx.x; t < 4096; t += blockDim.x)
        if (h[t]) atomicAdd(&hist[t], h[t]);
    // ---- last-block-standing does the scan (atomic handshake: device-coherent) ----
    __threadfence();
    __syncthreads();
    if (threadIdx.x == 0) lastblk = atomicAdd(&hdr[7], 1u);
    __syncthreads();
    if (lastblk != gridDim.x - 1) return;
    if (threadIdx.x >= 64) return;
    int lane = threadIdx.x;             // one wave: 64 lanes x 64 bins
    int base = 4096 - 64 * (lane + 1);  // lane 0 = topmost segment
    u32 v[64];
    u32 segsum = 0;
#pragma unroll
    for (int j = 0; j < 64; j++) { v[j] = atomicAdd(&hist[base + j], 0u); segsum += v[j]; }
    u32 incl = segsum;
    for (int off = 1; off < 64; off <<= 1) {
        u32 t = (u32)__shfl_up((int)incl, off);
        if (lane >= off) incl += t;
    }
    u32 excl = incl - segsum;           // elements in bins above my segment
    u32 total = (u32)__shfl((int)incl, 63);
    // in-place suffix offsets: hist[b] := #elements in bins > b
    u32 run = excl;
#pragma unroll
    for (int j = 63; j >= 0; j--) { hist[base + j] = run; run += v[j]; }
    if (lane == 0) hdr[6] = total;
    if (total < (u32)TK) {
        if (lane == 0) { hdr[3] = 0; hdr[5] = total; }   // take-all
        return;
    }
    if ((excl < (u32)TK) && (incl >= (u32)TK)) {
        u32 cum = excl;
#pragma unroll
        for (int j = 63; j >= 0; j--) {
            u32 nc = cum + v[j];
            if (nc >= (u32)TK) { hdr[3] = (u32)(base + j); hdr[5] = nc; break; }
            cum = nc;
        }
    }
}

// ---- collect: coalesced float4 stream, bucket-scatter at/above pivot bin ----
__global__ void k_collect(const float* __restrict__ scores,
                          const float* __restrict__ center,
                          int R, const u32* __restrict__ hdr,
                          const u32* __restrict__ offs, u32* __restrict__ binpos,
                          u64* __restrict__ buf) {
    u32 thr = hdr[3];
    int total_e = R * 11;
    int nq = total_e >> 2;
    int stride = gridDim.x * blockDim.x;
    int tid0 = blockIdx.x * blockDim.x + threadIdx.x;
    for (int q = tid0; q < nq; q += stride) {
        float4 v4 = ((const float4*)scores)[q];
        int e = q << 2;
        float vv[4] = {v4.x, v4.y, v4.z, v4.w};
#pragma unroll
        for (int j = 0; j < 4; j++) {
            int e2 = e + j;
            u32 r = (u32)(((u64)(u32)e2 * MAGIC11) >> 35);
            u32 c = (u32)e2 - r * 11u;
            if (c != 0u) {
                float s = __fmul_rn(vv[j], center[r]);
                if (s > SCORE_THR) {
                    u32 key = __float_as_uint(s);
                    int b = (int)(key >> 14) - BASE14;
                    b = min(max(b, 0), 4095);
                    if ((u32)b >= thr) {
                        u32 slot = atomicAdd(&binpos[b], 1u);
                        u32 pos = offs[b] + slot;
                        if (pos < CAP) {
                            u32 idx = r * 10u + (c - 1u);
                            buf[pos] = ((u64)key << 32) | (u64)(~idx);
                        }
                    }
                }
            }
        }
    }
    if (tid0 == 0) {                      // tail (total_e % 4)
        for (int e2 = nq << 2; e2 < total_e; e2++) {
            u32 r = (u32)(((u64)(u32)e2 * MAGIC11) >> 35);
            u32 c = (u32)e2 - r * 11u;
            if (c != 0u) {
                float s = __fmul_rn(scores[e2], center[r]);
                if (s > SCORE_THR) {
                    u32 key = __float_as_uint(s);
                    int b = (int)(key >> 14) - BASE14;
                    b = min(max(b, 0), 4095);
                    if ((u32)b >= thr) {
                        u32 slot = atomicAdd(&binpos[b], 1u);
                        u32 pos = offs[b] + slot;
                        if (pos < CAP) {
                            u32 idx = r * 10u + (c - 1u);
                            buf[pos] = ((u64)key << 32) | (u64)(~idx);
                        }
                    }
                }
            }
        }
    }
}

// ---- per-ELEMENT rank (LDS-staged, O(run) per element) + scatter-write ----
__global__ __launch_bounds__(1024) void k_rank(
        const float* __restrict__ boxes, const u32* __restrict__ offs,
        const u32* __restrict__ hdr, const u64* __restrict__ buf,
        float* __restrict__ cand_bx, float* __restrict__ nms_bx,
        float* __restrict__ vals) {
    __shared__ u64 kb[CAP];
    __shared__ u32 lo[4096];
    int tid = threadIdx.x;
    u32 n = hdr[5]; if (n > (u32)CAP) n = CAP;
    u32 total = hdr[6];
    for (int t = tid; t < CAP; t += 1024) kb[t] = (t < (int)n) ? buf[t] : 0ull;
    for (int t = tid; t < 4096; t += 1024) lo[t] = offs[t];
    __syncthreads();
    for (int i = tid; i < (int)n; i += 1024) {
        u64 x = kb[i];
        u32 key = (u32)(x >> 32);
        int b = (int)(key >> 14) - BASE14;
        b = min(max(b, 0), 4095);
        u32 start = lo[b];
        u32 end = (b > 0) ? lo[b - 1] : total;
        if (end > (u32)CAP) end = CAP;
        u32 rk = start;                 // global rank = bin start + within-bin rank
        for (u32 j = start; j < end; j++) rk += (kb[j] > x) ? 1u : 0u;
        if (rk < (u32)TK) {
            u32 idx = ~(u32)x;
            u32 r = idx / 10u, cls = idx % 10u;
            const float* bp = boxes + (size_t)r * 4;
            float c0 = fminf(fmaxf(bp[0], 0.f), 1920.f);
            float c1 = fminf(fmaxf(bp[1], 0.f), 1080.f);
            float c2 = fminf(fmaxf(bp[2], 0.f), 1920.f);
            float c3 = fminf(fmaxf(bp[3], 0.f), 1080.f);
            float offv = __fmul_rn((float)cls, 3001.0f);  // exact: small ints
            cand_bx[rk * 4 + 0] = c0; cand_bx[rk * 4 + 1] = c1;
            cand_bx[rk * 4 + 2] = c2; cand_bx[rk * 4 + 3] = c3;
            nms_bx[rk * 4 + 0] = __fadd_rn(c0, offv);
            nms_bx[rk * 4 + 1] = __fadd_rn(c1, offv);
            nms_bx[rk * 4 + 2] = __fadd_rn(c2, offv);
            nms_bx[rk * 4 + 3] = __fadd_rn(c3, offv);
            vals[rk] = __uint_as_float(key);
        }
    }
}

// ---- suppression bitmask: mask[row][word] over 2048x2048 pairs ----
__global__ void k_mask(const float* __restrict__ nms_bx, u32* __restrict__ mask) {
    __shared__ float4 cb[64];
    __shared__ float ca[64];
    int tid = threadIdx.x;
    int colbase = blockIdx.x * 64, rowbase = blockIdx.y * 64;
    float4 c = ((const float4*)nms_bx)[colbase + tid];
    cb[tid] = c;
    ca[tid] = __fmul_rn(fmaxf(__fsub_rn(c.z, c.x), 0.f),
                        fmaxf(__fsub_rn(c.w, c.y), 0.f));
    int row = rowbase + tid;
    float4 rb = ((const float4*)nms_bx)[row];
    float rarea = __fmul_rn(fmaxf(__fsub_rn(rb.z, rb.x), 0.f),
                            fmaxf(__fsub_rn(rb.w, rb.y), 0.f));
    __syncthreads();
    u32 w0 = 0, w1 = 0;
    for (int cc = 0; cc < 64; cc++) {
        int col = colbase + cc;
        if (col > row) {
            float4 cbv = cb[cc];
            float ltx = fmaxf(rb.x, cbv.x), lty = fmaxf(rb.y, cbv.y);
            float rbx = fminf(rb.z, cbv.z), rby = fminf(rb.w, cbv.w);
            float w = fmaxf(__fsub_rn(rbx, ltx), 0.f);
            float h = fmaxf(__fsub_rn(rby, lty), 0.f);
            float inter = __fmul_rn(w, h);
            // ref order: ((area_i + area_j) - inter) + 1e-9
            float denom = __fadd_rn(__fsub_rn(__fadd_rn(rarea, ca[cc]), inter), 1e-9f);
            float iou = __fdiv_rn(inter, denom);
            if (iou > NMS_THR) {
                if (cc < 32) w0 |= 1u << cc; else w1 |= 1u << (cc - 32);
            }
        }
    }
    mask[row * 64 + blockIdx.x * 2 + 0] = w0;
    mask[row * 64 + blockIdx.x * 2 + 1] = w1;
}

// ---- greedy scan: word-parallel (64 broadcasts total) + output write ----
__global__ void k_final(const u32* __restrict__ mask, const float* __restrict__ vals,
                        const float* __restrict__ cand_bx, float* __restrict__ out) {
    int lane = threadIdx.x;  // lane owns keep/removed bits [lane*32, lane*32+32)
    u32 validw = 0;
#pragma unroll
    for (int b = 0; b < 32; b++)
        validw |= (vals[lane * 32 + b] > SCORE_THR ? 1u : 0u) << b;
    u32 removed = 0, keepw = 0;
    u32 bufA[32], bufB[32];
#pragma unroll
    for (int j = 0; j < 32; j++) bufA[j] = mask[j * 64 + lane];
    for (int w = 0; w < 64; w += 2) {
#pragma unroll
        for (int j = 0; j < 32; j++) bufB[j] = mask[((w + 1) * 32 + j) * 64 + lane];
        {
            u32 alive = validw & ~removed;
#pragma unroll
            for (int j = 0; j < 32; j++)
                alive &= ((alive >> j) & 1u) ? ~bufA[j] : 0xFFFFFFFFu;
            u32 kw = (u32)__shfl((int)alive, w);
            if (lane == w) keepw = kw;
            u32 acc = 0;
#pragma unroll
            for (int j = 0; j < 32; j++) acc |= ((kw >> j) & 1u) ? bufA[j] : 0u;
            removed |= acc;
        }
        if (w + 2 < 64) {
#pragma unroll
            for (int j = 0; j < 32; j++) bufA[j] = mask[((w + 2) * 32 + j) * 64 + lane];
        }
        {
            u32 alive = validw & ~removed;
#pragma unroll
            for (int j = 0; j < 32; j++)
                alive &= ((alive >> j) & 1u) ? ~bufB[j] : 0xFFFFFFFFu;
            u32 kw = (u32)__shfl((int)alive, w + 1);
            if (lane == w + 1) keepw = kw;
            u32 acc = 0;
#pragma unroll
            for (int j = 0; j < 32; j++) acc |= ((kw >> j) & 1u) ? bufB[j] : 0u;
            removed |= acc;
        }
    }
#pragma unroll
    for (int b = 0; b < 32; b++) {
        int i = lane * 32 + b;
        bool kp = (keepw >> b) & 1u;
        const float4 bx = ((const float4*)cand_bx)[i];
        out[i * 5 + 0] = kp ? bx.x : 0.f;
        out[i * 5 + 1] = kp ? bx.y : 0.f;
        out[i * 5 + 2] = kp ? bx.z : 0.f;
        out[i * 5 + 3] = kp ? bx.w : 0.f;
        out[i * 5 + 4] = kp ? vals[i] : 0.f;
    }
}

extern "C" void kernel_launch(void* const* d_in, const int* in_sizes, int n_in,
                              void* d_out, int out_size, void* d_ws, size_t ws_size,
                              hipStream_t stream) {
    const float* boxes = (const float*)d_in[0];
    const float* scores = (const float*)d_in[1];
    const float* center = (const float*)d_in[2];
    float* out = (float*)d_out;
    int R = in_sizes[2];

    char* w = (char*)d_ws;
    u32* offs   = (u32*)(w + WS_OFFS);
    u32* binpos = (u32*)(w + WS_BINPOS);
    u32* hdr    = (u32*)(w + WS_HDR);
    float* cbx  = (float*)(w + WS_CBX);
    float* nbx  = (float*)(w + WS_NBX);
    float* vls  = (float*)(w + WS_VALS);
    u32* mask   = (u32*)(w + WS_MASK);
    u64* buf    = (u64*)(w + WS_BUF);   // aliases mask (disjoint lifetime)

    // zero hist + binpos + hdr + cand/nms/vals padding (ws poisoned 0xAA per call)
    hipMemsetAsync(w, 0, WS_MASK, stream);

    k_hist<<<1024, 256, 0, stream>>>(scores, center, R, offs, hdr);
    k_collect<<<1024, 256, 0, stream>>>(scores, center, R, hdr, offs, binpos, buf);
    k_rank<<<1, 1024, 0, stream>>>(boxes, offs, hdr, buf, cbx, nbx, vls);
    k_mask<<<dim3(32, 32), 64, 0, stream>>>(nbx, mask);
    k_final<<<1, 64, 0, stream>>>(mask, vls, cbx, out);
}

// Round 6
// 199.163 us; speedup vs baseline: 1.3355x; 1.1580x over previous
//
#include <hip/hip_runtime.h>
#include <stdint.h>

typedef unsigned int u32;
typedef unsigned long long u64;

#define SCORE_THR 0.05f
#define NMS_THR   0.5f
#define TK        2048
#define CAP       4096
#define BASE14    ((int)(0x3D4CCCCDu >> 14))   // (bits of 0.05f) >> 14 = 62771
#define MAGIC11   3123612579ull                // ceil(2^35/11); exact /11 for e < 2^35
#define NREP      8

// ---------------- ws layout (bytes) ----------------
// 0      : offs    u32[4096]  (fully written by k_scan)
// 16384  : binpos  u32[4096]  (zeroed)
// 32768  : hdr     u32[64]    (zeroed) hdr[3]=pivot bin hdr[5]=n>=pivot hdr[6]=total
// 33024  : cand_bx f32[2048*4] (zeroed: padding slots)
// 65792  : nms_bx  f32[2048*4] (zeroed)
// 98560  : vals    f32[2048]   (zeroed)
// 106752 : mask    u32[2048*64] (512 KB)
//          hrep u32[8][4096] (128 KB) ALIASES mask[0:128K]  (dead after k_scan)
//          buf  u64[4096]    (32 KB)  ALIASES mask[128K:160K] (dead before k_mask)
#define WS_OFFS   0
#define WS_BINPOS 16384
#define WS_HDR    32768
#define WS_CBX    33024
#define WS_NBX    65792
#define WS_VALS   98560
#define WS_MASK   106752
#define WS_HREP   106752
#define WS_BUF    237824

// ---- histogram over key bits [30:14]: contiguous chunks, 4-wide float4 MLP,
//      LDS hist, merge into 8 replicated global hists (contention /8) ----
__global__ void k_hist(const float* __restrict__ scores,
                       const float* __restrict__ center,
                       int R, u32* __restrict__ hrep) {
    __shared__ u32 h[4096];
    for (int t = threadIdx.x; t < 4096; t += blockDim.x) h[t] = 0;
    __syncthreads();
    int total_e = R * 11;
    int nq = total_e >> 2;
    int qpb = (nq + (int)gridDim.x - 1) / (int)gridDim.x;
    int start = (int)blockIdx.x * qpb;
    int end = start + qpb; if (end > nq) end = nq;
    int bd = (int)blockDim.x;
    for (int q = start + (int)threadIdx.x; q < end; q += 4 * bd) {
        int q1 = q + bd, q2 = q + 2 * bd, q3 = q + 3 * bd;
        float4 va, vb, vc, vd;
        bool ga = true, gb = q1 < end, gc = q2 < end, gd = q3 < end;
        va = ((const float4*)scores)[q];
        if (gb) vb = ((const float4*)scores)[q1];
        if (gc) vc = ((const float4*)scores)[q2];
        if (gd) vd = ((const float4*)scores)[q3];
#define HPROC(g, qq, v4)                                                   \
        if (g) {                                                           \
            float vv[4] = {v4.x, v4.y, v4.z, v4.w};                        \
            _Pragma("unroll")                                              \
            for (int j = 0; j < 4; j++) {                                  \
                u32 e2 = ((u32)(qq) << 2) + (u32)j;                        \
                u32 r = (u32)(((u64)e2 * MAGIC11) >> 35);                  \
                u32 c = e2 - r * 11u;                                      \
                if (c != 0u) {                                             \
                    float s = __fmul_rn(vv[j], center[r]);                 \
                    if (s > SCORE_THR) {                                   \
                        u32 key = __float_as_uint(s);                      \
                        int b = (int)(key >> 14) - BASE14;                 \
                        b = min(max(b, 0), 4095);                          \
                        atomicAdd(&h[b], 1u);                              \
                    }                                                      \
                }                                                          \
            }                                                              \
        }
        HPROC(ga, q, va) HPROC(gb, q1, vb) HPROC(gc, q2, vc) HPROC(gd, q3, vd)
#undef HPROC
    }
    // tail (total_e % 4) — R*11 % 4 == 0 for R=500000, kept for generality
    if (blockIdx.x == 0 && threadIdx.x == 0) {
        for (int e2 = nq << 2; e2 < total_e; e2++) {
            u32 r = (u32)(((u64)(u32)e2 * MAGIC11) >> 35);
            u32 c = (u32)e2 - r * 11u;
            if (c != 0u) {
                float s = __fmul_rn(scores[e2], center[r]);
                if (s > SCORE_THR) {
                    u32 key = __float_as_uint(s);
                    int b = (int)(key >> 14) - BASE14;
                    b = min(max(b, 0), 4095);
                    atomicAdd(&h[b], 1u);
                }
            }
        }
    }
    __syncthreads();
    u32* hout = hrep + (size_t)(blockIdx.x & (NREP - 1)) * 4096;
    for (int t = threadIdx.x; t < 4096; t += blockDim.x)
        if (h[t]) atomicAdd(&hout[t], h[t]);
}

// ---- scan (one wave): sum 8 replicas (plain loads), suffix offsets, pivot ----
__global__ void k_scan(const u32* __restrict__ hrep, u32* __restrict__ offs,
                       u32* hdr) {
    int lane = threadIdx.x;             // 64 lanes x 64 bins
    int base = 4096 - 64 * (lane + 1);  // lane 0 = topmost segment
    u32 v[64];
    u32 segsum = 0;
#pragma unroll
    for (int j = 0; j < 64; j++) {
        u32 s = 0;
#pragma unroll
        for (int i = 0; i < NREP; i++) s += hrep[i * 4096 + base + j];
        v[j] = s; segsum += s;
    }
    u32 incl = segsum;
    for (int off = 1; off < 64; off <<= 1) {
        u32 t = (u32)__shfl_up((int)incl, off);
        if (lane >= off) incl += t;
    }
    u32 excl = incl - segsum;           // elements in bins above my segment
    u32 total = (u32)__shfl((int)incl, 63);
    u32 run = excl;                     // offs[b] = #elements in bins > b
#pragma unroll
    for (int j = 63; j >= 0; j--) { offs[base + j] = run; run += v[j]; }
    if (lane == 0) hdr[6] = total;
    if (total < (u32)TK) {
        if (lane == 0) { hdr[3] = 0; hdr[5] = total; }   // take-all
        return;
    }
    if ((excl < (u32)TK) && (incl >= (u32)TK)) {
        u32 cum = excl;
#pragma unroll
        for (int j = 63; j >= 0; j--) {
            u32 nc = cum + v[j];
            if (nc >= (u32)TK) { hdr[3] = (u32)(base + j); hdr[5] = nc; break; }
            cum = nc;
        }
    }
}

// ---- collect: contiguous chunks, 4-wide MLP, bucket-scatter >= pivot ----
__global__ void k_collect(const float* __restrict__ scores,
                          const float* __restrict__ center,
                          int R, const u32* __restrict__ hdr,
                          const u32* __restrict__ offs, u32* __restrict__ binpos,
                          u64* __restrict__ buf) {
    u32 thr = hdr[3];
    int total_e = R * 11;
    int nq = total_e >> 2;
    int qpb = (nq + (int)gridDim.x - 1) / (int)gridDim.x;
    int start = (int)blockIdx.x * qpb;
    int end = start + qpb; if (end > nq) end = nq;
    int bd = (int)blockDim.x;
    for (int q = start + (int)threadIdx.x; q < end; q += 4 * bd) {
        int q1 = q + bd, q2 = q + 2 * bd, q3 = q + 3 * bd;
        float4 va, vb, vc, vd;
        bool ga = true, gb = q1 < end, gc = q2 < end, gd = q3 < end;
        va = ((const float4*)scores)[q];
        if (gb) vb = ((const float4*)scores)[q1];
        if (gc) vc = ((const float4*)scores)[q2];
        if (gd) vd = ((const float4*)scores)[q3];
#define CPROC(g, qq, v4)                                                   \
        if (g) {                                                           \
            float vv[4] = {v4.x, v4.y, v4.z, v4.w};                        \
            _Pragma("unroll")                                              \
            for (int j = 0; j < 4; j++) {                                  \
                u32 e2 = ((u32)(qq) << 2) + (u32)j;                        \
                u32 r = (u32)(((u64)e2 * MAGIC11) >> 35);                  \
                u32 c = e2 - r * 11u;                                      \
                if (c != 0u) {                                             \
                    float s = __fmul_rn(vv[j], center[r]);                 \
                    if (s > SCORE_THR) {                                   \
                        u32 key = __float_as_uint(s);                      \
                        int b = (int)(key >> 14) - BASE14;                 \
                        b = min(max(b, 0), 4095);                          \
                        if ((u32)b >= thr) {                               \
                            u32 slot = atomicAdd(&binpos[b], 1u);          \
                            u32 pos = offs[b] + slot;                      \
                            if (pos < CAP) {                               \
                                u32 idx = r * 10u + (c - 1u);              \
                                buf[pos] = ((u64)key << 32) | (u64)(~idx); \
                            }                                              \
                        }                                                  \
                    }                                                      \
                }                                                          \
            }                                                              \
        }
        CPROC(ga, q, va) CPROC(gb, q1, vb) CPROC(gc, q2, vc) CPROC(gd, q3, vd)
#undef CPROC
    }
    if (blockIdx.x == 0 && threadIdx.x == 0) {       // tail (total_e % 4)
        for (int e2 = nq << 2; e2 < total_e; e2++) {
            u32 r = (u32)(((u64)(u32)e2 * MAGIC11) >> 35);
            u32 c = (u32)e2 - r * 11u;
            if (c != 0u) {
                float s = __fmul_rn(scores[e2], center[r]);
                if (s > SCORE_THR) {
                    u32 key = __float_as_uint(s);
                    int b = (int)(key >> 14) - BASE14;
                    b = min(max(b, 0), 4095);
                    if ((u32)b >= thr) {
                        u32 slot = atomicAdd(&binpos[b], 1u);
                        u32 pos = offs[b] + slot;
                        if (pos < CAP) {
                            u32 idx = r * 10u + (c - 1u);
                            buf[pos] = ((u64)key << 32) | (u64)(~idx);
                        }
                    }
                }
            }
        }
    }
}

// ---- per-ELEMENT rank (LDS-staged, O(run) per element) + scatter-write ----
__global__ __launch_bounds__(1024) void k_rank(
        const float* __restrict__ boxes, const u32* __restrict__ offs,
        const u32* __restrict__ hdr, const u64* __restrict__ buf,
        float* __restrict__ cand_bx, float* __restrict__ nms_bx,
        float* __restrict__ vals) {
    __shared__ u64 kb[CAP];
    __shared__ u32 lo[4096];
    int tid = threadIdx.x;
    u32 n = hdr[5]; if (n > (u32)CAP) n = CAP;
    u32 total = hdr[6];
    for (int t = tid; t < CAP; t += 1024) kb[t] = (t < (int)n) ? buf[t] : 0ull;
    for (int t = tid; t < 4096; t += 1024) lo[t] = offs[t];
    __syncthreads();
    for (int i = tid; i < (int)n; i += 1024) {
        u64 x = kb[i];
        u32 key = (u32)(x >> 32);
        int b = (int)(key >> 14) - BASE14;
        b = min(max(b, 0), 4095);
        u32 start = lo[b];
        u32 end = (b > 0) ? lo[b - 1] : total;
        if (end > (u32)CAP) end = CAP;
        u32 rk = start;                 // global rank = bin start + within-bin rank
        for (u32 j = start; j < end; j++) rk += (kb[j] > x) ? 1u : 0u;
        if (rk < (u32)TK) {
            u32 idx = ~(u32)x;
            u32 r = idx / 10u, cls = idx % 10u;
            const float* bp = boxes + (size_t)r * 4;
            float c0 = fminf(fmaxf(bp[0], 0.f), 1920.f);
            float c1 = fminf(fmaxf(bp[1], 0.f), 1080.f);
            float c2 = fminf(fmaxf(bp[2], 0.f), 1920.f);
            float c3 = fminf(fmaxf(bp[3], 0.f), 1080.f);
            float offv = __fmul_rn((float)cls, 3001.0f);  // exact: small ints
            cand_bx[rk * 4 + 0] = c0; cand_bx[rk * 4 + 1] = c1;
            cand_bx[rk * 4 + 2] = c2; cand_bx[rk * 4 + 3] = c3;
            nms_bx[rk * 4 + 0] = __fadd_rn(c0, offv);
            nms_bx[rk * 4 + 1] = __fadd_rn(c1, offv);
            nms_bx[rk * 4 + 2] = __fadd_rn(c2, offv);
            nms_bx[rk * 4 + 3] = __fadd_rn(c3, offv);
            vals[rk] = __uint_as_float(key);
        }
    }
}

// ---- suppression bitmask: mask[row][word] over 2048x2048 pairs ----
__global__ void k_mask(const float* __restrict__ nms_bx, u32* __restrict__ mask) {
    __shared__ float4 cb[64];
    __shared__ float ca[64];
    int tid = threadIdx.x;
    int colbase = blockIdx.x * 64, rowbase = blockIdx.y * 64;
    float4 c = ((const float4*)nms_bx)[colbase + tid];
    cb[tid] = c;
    ca[tid] = __fmul_rn(fmaxf(__fsub_rn(c.z, c.x), 0.f),
                        fmaxf(__fsub_rn(c.w, c.y), 0.f));
    int row = rowbase + tid;
    float4 rb = ((const float4*)nms_bx)[row];
    float rarea = __fmul_rn(fmaxf(__fsub_rn(rb.z, rb.x), 0.f),
                            fmaxf(__fsub_rn(rb.w, rb.y), 0.f));
    __syncthreads();
    u32 w0 = 0, w1 = 0;
    for (int cc = 0; cc < 64; cc++) {
        int col = colbase + cc;
        if (col > row) {
            float4 cbv = cb[cc];
            float ltx = fmaxf(rb.x, cbv.x), lty = fmaxf(rb.y, cbv.y);
            float rbx = fminf(rb.z, cbv.z), rby = fminf(rb.w, cbv.w);
            float w = fmaxf(__fsub_rn(rbx, ltx), 0.f);
            float h = fmaxf(__fsub_rn(rby, lty), 0.f);
            float inter = __fmul_rn(w, h);
            // ref order: ((area_i + area_j) - inter) + 1e-9
            float denom = __fadd_rn(__fsub_rn(__fadd_rn(rarea, ca[cc]), inter), 1e-9f);
            float iou = __fdiv_rn(inter, denom);
            if (iou > NMS_THR) {
                if (cc < 32) w0 |= 1u << cc; else w1 |= 1u << (cc - 32);
            }
        }
    }
    mask[row * 64 + blockIdx.x * 2 + 0] = w0;
    mask[row * 64 + blockIdx.x * 2 + 1] = w1;
}

// ---- greedy scan: word-parallel (64 broadcasts total) + output write ----
__global__ void k_final(const u32* __restrict__ mask, const float* __restrict__ vals,
                        const float* __restrict__ cand_bx, float* __restrict__ out) {
    int lane = threadIdx.x;  // lane owns keep/removed bits [lane*32, lane*32+32)
    u32 validw = 0;
#pragma unroll
    for (int b = 0; b < 32; b++)
        validw |= (vals[lane * 32 + b] > SCORE_THR ? 1u : 0u) << b;
    u32 removed = 0, keepw = 0;
    u32 bufA[32], bufB[32];
#pragma unroll
    for (int j = 0; j < 32; j++) bufA[j] = mask[j * 64 + lane];
    for (int w = 0; w < 64; w += 2) {
#pragma unroll
        for (int j = 0; j < 32; j++) bufB[j] = mask[((w + 1) * 32 + j) * 64 + lane];
        {
            u32 alive = validw & ~removed;
#pragma unroll
            for (int j = 0; j < 32; j++)
                alive &= ((alive >> j) & 1u) ? ~bufA[j] : 0xFFFFFFFFu;
            u32 kw = (u32)__shfl((int)alive, w);
            if (lane == w) keepw = kw;
            u32 acc = 0;
#pragma unroll
            for (int j = 0; j < 32; j++) acc |= ((kw >> j) & 1u) ? bufA[j] : 0u;
            removed |= acc;
        }
        if (w + 2 < 64) {
#pragma unroll
            for (int j = 0; j < 32; j++) bufA[j] = mask[((w + 2) * 32 + j) * 64 + lane];
        }
        {
            u32 alive = validw & ~removed;
#pragma unroll
            for (int j = 0; j < 32; j++)
                alive &= ((alive >> j) & 1u) ? ~bufB[j] : 0xFFFFFFFFu;
            u32 kw = (u32)__shfl((int)alive, w + 1);
            if (lane == w + 1) keepw = kw;
            u32 acc = 0;
#pragma unroll
            for (int j = 0; j < 32; j++) acc |= ((kw >> j) & 1u) ? bufB[j] : 0u;
            removed |= acc;
        }
    }
#pragma unroll
    for (int b = 0; b < 32; b++) {
        int i = lane * 32 + b;
        bool kp = (keepw >> b) & 1u;
        const float4 bx = ((const float4*)cand_bx)[i];
        out[i * 5 + 0] = kp ? bx.x : 0.f;
        out[i * 5 + 1] = kp ? bx.y : 0.f;
        out[i * 5 + 2] = kp ? bx.z : 0.f;
        out[i * 5 + 3] = kp ? bx.w : 0.f;
        out[i * 5 + 4] = kp ? vals[i] : 0.f;
    }
}

extern "C" void kernel_launch(void* const* d_in, const int* in_sizes, int n_in,
                              void* d_out, int out_size, void* d_ws, size_t ws_size,
                              hipStream_t stream) {
    const float* boxes = (const float*)d_in[0];
    const float* scores = (const float*)d_in[1];
    const float* center = (const float*)d_in[2];
    float* out = (float*)d_out;
    int R = in_sizes[2];

    char* w = (char*)d_ws;
    u32* offs   = (u32*)(w + WS_OFFS);
    u32* binpos = (u32*)(w + WS_BINPOS);
    u32* hdr    = (u32*)(w + WS_HDR);
    float* cbx  = (float*)(w + WS_CBX);
    float* nbx  = (float*)(w + WS_NBX);
    float* vls  = (float*)(w + WS_VALS);
    u32* mask   = (u32*)(w + WS_MASK);
    u32* hrep   = (u32*)(w + WS_HREP);  // aliases mask[0:128K]  (dead after k_scan)
    u64* buf    = (u64*)(w + WS_BUF);   // aliases mask[128K:160K] (dead before k_mask)

    // zero binpos+hdr+cand/nms/vals padding + hrep (ws poisoned 0xAA per call)
    hipMemsetAsync(w, 0, WS_BUF, stream);

    k_hist<<<256, 256, 0, stream>>>(scores, center, R, hrep);
    k_scan<<<1, 64, 0, stream>>>(hrep, offs, hdr);
    k_collect<<<256, 256, 0, stream>>>(scores, center, R, hdr, offs, binpos, buf);
    k_rank<<<1, 1024, 0, stream>>>(boxes, offs, hdr, buf, cbx, nbx, vls);
    k_mask<<<dim3(32, 32), 64, 0, stream>>>(nbx, mask);
    k_final<<<1, 64, 0, stream>>>(mask, vls, cbx, out);
}

// Round 7
// 193.135 us; speedup vs baseline: 1.3772x; 1.0312x over previous
//
#include <hip/hip_runtime.h>
#include <stdint.h>

typedef unsigned int u32;
typedef unsigned long long u64;

#define SCORE_THR 0.05f
#define NMS_THR   0.5f
#define TK        2048
#define CAP       4096
#define BASE14    ((int)(0x3D4CCCCDu >> 14))   // (bits of 0.05f) >> 14 = 62771
#define MAGIC11   3123612579ull                // ceil(2^35/11); exact /11 for e < 2^35
#define NREP      8

// ---------------- ws layout (bytes) ----------------
// 0      : offs    u32[4096]  (fully written by k_scan)
// 16384  : binpos  u32[4096]  (zeroed)
// 32768  : hdr     u32[64]    (zeroed) hdr[3]=pivot bin hdr[5]=n>=pivot hdr[6]=total
// 33024  : cand_bx f32[2048*4] (zeroed: padding slots)
// 65792  : nms_bx  f32[2048*4] (zeroed)
// 98560  : vals    f32[2048]   (zeroed)
// 106752 : maskT   u32[64][2048] (512 KB, COLUMN-major: maskT[colword][row])
//          hrep u32[8][4096] (128 KB) ALIASES maskT[0:128K]  (dead after k_scan)
//          buf  u64[4096]    (32 KB)  ALIASES maskT[128K:160K] (dead before k_mask)
#define WS_OFFS   0
#define WS_BINPOS 16384
#define WS_HDR    32768
#define WS_CBX    33024
#define WS_NBX    65792
#define WS_VALS   98560
#define WS_MASK   106752
#define WS_HREP   106752
#define WS_BUF    237824

// ---- histogram over key bits [30:14]: contiguous chunks, 4-wide float4 MLP,
//      LDS hist, merge into 8 replicated global hists (contention /8) ----
__global__ void k_hist(const float* __restrict__ scores,
                       const float* __restrict__ center,
                       int R, u32* __restrict__ hrep) {
    __shared__ u32 h[4096];
    for (int t = threadIdx.x; t < 4096; t += blockDim.x) h[t] = 0;
    __syncthreads();
    int total_e = R * 11;
    int nq = total_e >> 2;
    int qpb = (nq + (int)gridDim.x - 1) / (int)gridDim.x;
    int start = (int)blockIdx.x * qpb;
    int end = start + qpb; if (end > nq) end = nq;
    int bd = (int)blockDim.x;
    for (int q = start + (int)threadIdx.x; q < end; q += 4 * bd) {
        int q1 = q + bd, q2 = q + 2 * bd, q3 = q + 3 * bd;
        float4 va, vb, vc, vd;
        bool ga = true, gb = q1 < end, gc = q2 < end, gd = q3 < end;
        va = ((const float4*)scores)[q];
        if (gb) vb = ((const float4*)scores)[q1];
        if (gc) vc = ((const float4*)scores)[q2];
        if (gd) vd = ((const float4*)scores)[q3];
#define HPROC(g, qq, v4)                                                   \
        if (g) {                                                           \
            float vv[4] = {v4.x, v4.y, v4.z, v4.w};                        \
            _Pragma("unroll")                                              \
            for (int j = 0; j < 4; j++) {                                  \
                u32 e2 = ((u32)(qq) << 2) + (u32)j;                        \
                u32 r = (u32)(((u64)e2 * MAGIC11) >> 35);                  \
                u32 c = e2 - r * 11u;                                      \
                if (c != 0u) {                                             \
                    float s = __fmul_rn(vv[j], center[r]);                 \
                    if (s > SCORE_THR) {                                   \
                        u32 key = __float_as_uint(s);                      \
                        int b = (int)(key >> 14) - BASE14;                 \
                        b = min(max(b, 0), 4095);                          \
                        atomicAdd(&h[b], 1u);                              \
                    }                                                      \
                }                                                          \
            }                                                              \
        }
        HPROC(ga, q, va) HPROC(gb, q1, vb) HPROC(gc, q2, vc) HPROC(gd, q3, vd)
#undef HPROC
    }
    // tail (total_e % 4) — R*11 % 4 == 0 for R=500000, kept for generality
    if (blockIdx.x == 0 && threadIdx.x == 0) {
        for (int e2 = nq << 2; e2 < total_e; e2++) {
            u32 r = (u32)(((u64)(u32)e2 * MAGIC11) >> 35);
            u32 c = (u32)e2 - r * 11u;
            if (c != 0u) {
                float s = __fmul_rn(scores[e2], center[r]);
                if (s > SCORE_THR) {
                    u32 key = __float_as_uint(s);
                    int b = (int)(key >> 14) - BASE14;
                    b = min(max(b, 0), 4095);
                    atomicAdd(&h[b], 1u);
                }
            }
        }
    }
    __syncthreads();
    u32* hout = hrep + (size_t)(blockIdx.x & (NREP - 1)) * 4096;
    for (int t = threadIdx.x; t < 4096; t += blockDim.x)
        if (h[t]) atomicAdd(&hout[t], h[t]);
}

// ---- scan (one wave): sum 8 replicas (plain loads), suffix offsets, pivot ----
__global__ void k_scan(const u32* __restrict__ hrep, u32* __restrict__ offs,
                       u32* hdr) {
    int lane = threadIdx.x;             // 64 lanes x 64 bins
    int base = 4096 - 64 * (lane + 1);  // lane 0 = topmost segment
    u32 v[64];
    u32 segsum = 0;
#pragma unroll
    for (int j = 0; j < 64; j++) {
        u32 s = 0;
#pragma unroll
        for (int i = 0; i < NREP; i++) s += hrep[i * 4096 + base + j];
        v[j] = s; segsum += s;
    }
    u32 incl = segsum;
    for (int off = 1; off < 64; off <<= 1) {
        u32 t = (u32)__shfl_up((int)incl, off);
        if (lane >= off) incl += t;
    }
    u32 excl = incl - segsum;           // elements in bins above my segment
    u32 total = (u32)__shfl((int)incl, 63);
    u32 run = excl;                     // offs[b] = #elements in bins > b
#pragma unroll
    for (int j = 63; j >= 0; j--) { offs[base + j] = run; run += v[j]; }
    if (lane == 0) hdr[6] = total;
    if (total < (u32)TK) {
        if (lane == 0) { hdr[3] = 0; hdr[5] = total; }   // take-all
        return;
    }
    if ((excl < (u32)TK) && (incl >= (u32)TK)) {
        u32 cum = excl;
#pragma unroll
        for (int j = 63; j >= 0; j--) {
            u32 nc = cum + v[j];
            if (nc >= (u32)TK) { hdr[3] = (u32)(base + j); hdr[5] = nc; break; }
            cum = nc;
        }
    }
}

// ---- collect: contiguous chunks, 4-wide MLP, bucket-scatter >= pivot ----
__global__ void k_collect(const float* __restrict__ scores,
                          const float* __restrict__ center,
                          int R, const u32* __restrict__ hdr,
                          const u32* __restrict__ offs, u32* __restrict__ binpos,
                          u64* __restrict__ buf) {
    u32 thr = hdr[3];
    int total_e = R * 11;
    int nq = total_e >> 2;
    int qpb = (nq + (int)gridDim.x - 1) / (int)gridDim.x;
    int start = (int)blockIdx.x * qpb;
    int end = start + qpb; if (end > nq) end = nq;
    int bd = (int)blockDim.x;
    for (int q = start + (int)threadIdx.x; q < end; q += 4 * bd) {
        int q1 = q + bd, q2 = q + 2 * bd, q3 = q + 3 * bd;
        float4 va, vb, vc, vd;
        bool ga = true, gb = q1 < end, gc = q2 < end, gd = q3 < end;
        va = ((const float4*)scores)[q];
        if (gb) vb = ((const float4*)scores)[q1];
        if (gc) vc = ((const float4*)scores)[q2];
        if (gd) vd = ((const float4*)scores)[q3];
#define CPROC(g, qq, v4)                                                   \
        if (g) {                                                           \
            float vv[4] = {v4.x, v4.y, v4.z, v4.w};                        \
            _Pragma("unroll")                                              \
            for (int j = 0; j < 4; j++) {                                  \
                u32 e2 = ((u32)(qq) << 2) + (u32)j;                        \
                u32 r = (u32)(((u64)e2 * MAGIC11) >> 35);                  \
                u32 c = e2 - r * 11u;                                      \
                if (c != 0u) {                                             \
                    float s = __fmul_rn(vv[j], center[r]);                 \
                    if (s > SCORE_THR) {                                   \
                        u32 key = __float_as_uint(s);                      \
                        int b = (int)(key >> 14) - BASE14;                 \
                        b = min(max(b, 0), 4095);                          \
                        if ((u32)b >= thr) {                               \
                            u32 slot = atomicAdd(&binpos[b], 1u);          \
                            u32 pos = offs[b] + slot;                      \
                            if (pos < CAP) {                               \
                                u32 idx = r * 10u + (c - 1u);              \
                                buf[pos] = ((u64)key << 32) | (u64)(~idx); \
                            }                                              \
                        }                                                  \
                    }                                                      \
                }                                                          \
            }                                                              \
        }
        CPROC(ga, q, va) CPROC(gb, q1, vb) CPROC(gc, q2, vc) CPROC(gd, q3, vd)
#undef CPROC
    }
    if (blockIdx.x == 0 && threadIdx.x == 0) {       // tail (total_e % 4)
        for (int e2 = nq << 2; e2 < total_e; e2++) {
            u32 r = (u32)(((u64)(u32)e2 * MAGIC11) >> 35);
            u32 c = (u32)e2 - r * 11u;
            if (c != 0u) {
                float s = __fmul_rn(scores[e2], center[r]);
                if (s > SCORE_THR) {
                    u32 key = __float_as_uint(s);
                    int b = (int)(key >> 14) - BASE14;
                    b = min(max(b, 0), 4095);
                    if ((u32)b >= thr) {
                        u32 slot = atomicAdd(&binpos[b], 1u);
                        u32 pos = offs[b] + slot;
                        if (pos < CAP) {
                            u32 idx = r * 10u + (c - 1u);
                            buf[pos] = ((u64)key << 32) | (u64)(~idx);
                        }
                    }
                }
            }
        }
    }
}

// ---- per-ELEMENT rank (LDS-staged, O(run) per element) + scatter-write ----
__global__ __launch_bounds__(1024) void k_rank(
        const float* __restrict__ boxes, const u32* __restrict__ offs,
        const u32* __restrict__ hdr, const u64* __restrict__ buf,
        float* __restrict__ cand_bx, float* __restrict__ nms_bx,
        float* __restrict__ vals) {
    __shared__ u64 kb[CAP];
    __shared__ u32 lo[4096];
    int tid = threadIdx.x;
    u32 n = hdr[5]; if (n > (u32)CAP) n = CAP;
    u32 total = hdr[6];
    for (int t = tid; t < CAP; t += 1024) kb[t] = (t < (int)n) ? buf[t] : 0ull;
    for (int t = tid; t < 4096; t += 1024) lo[t] = offs[t];
    __syncthreads();
    for (int i = tid; i < (int)n; i += 1024) {
        u64 x = kb[i];
        u32 key = (u32)(x >> 32);
        int b = (int)(key >> 14) - BASE14;
        b = min(max(b, 0), 4095);
        u32 start = lo[b];
        u32 end = (b > 0) ? lo[b - 1] : total;
        if (end > (u32)CAP) end = CAP;
        u32 rk = start;                 // global rank = bin start + within-bin rank
        for (u32 j = start; j < end; j++) rk += (kb[j] > x) ? 1u : 0u;
        if (rk < (u32)TK) {
            u32 idx = ~(u32)x;
            u32 r = idx / 10u, cls = idx % 10u;
            const float* bp = boxes + (size_t)r * 4;
            float c0 = fminf(fmaxf(bp[0], 0.f), 1920.f);
            float c1 = fminf(fmaxf(bp[1], 0.f), 1080.f);
            float c2 = fminf(fmaxf(bp[2], 0.f), 1920.f);
            float c3 = fminf(fmaxf(bp[3], 0.f), 1080.f);
            float offv = __fmul_rn((float)cls, 3001.0f);  // exact: small ints
            cand_bx[rk * 4 + 0] = c0; cand_bx[rk * 4 + 1] = c1;
            cand_bx[rk * 4 + 2] = c2; cand_bx[rk * 4 + 3] = c3;
            nms_bx[rk * 4 + 0] = __fadd_rn(c0, offv);
            nms_bx[rk * 4 + 1] = __fadd_rn(c1, offv);
            nms_bx[rk * 4 + 2] = __fadd_rn(c2, offv);
            nms_bx[rk * 4 + 3] = __fadd_rn(c3, offv);
            vals[rk] = __uint_as_float(key);
        }
    }
}

// ---- suppression bitmask, COLUMN-major: maskT[colword][row] ----
__global__ void k_mask(const float* __restrict__ nms_bx, u32* __restrict__ maskT) {
    __shared__ float4 cb[64];
    __shared__ float ca[64];
    int tid = threadIdx.x;
    int colbase = blockIdx.x * 64, rowbase = blockIdx.y * 64;
    float4 c = ((const float4*)nms_bx)[colbase + tid];
    cb[tid] = c;
    ca[tid] = __fmul_rn(fmaxf(__fsub_rn(c.z, c.x), 0.f),
                        fmaxf(__fsub_rn(c.w, c.y), 0.f));
    int row = rowbase + tid;
    float4 rb = ((const float4*)nms_bx)[row];
    float rarea = __fmul_rn(fmaxf(__fsub_rn(rb.z, rb.x), 0.f),
                            fmaxf(__fsub_rn(rb.w, rb.y), 0.f));
    __syncthreads();
    u32 w0 = 0, w1 = 0;
    for (int cc = 0; cc < 64; cc++) {
        int col = colbase + cc;
        if (col > row) {
            float4 cbv = cb[cc];
            float ltx = fmaxf(rb.x, cbv.x), lty = fmaxf(rb.y, cbv.y);
            float rbx = fminf(rb.z, cbv.z), rby = fminf(rb.w, cbv.w);
            float w = fmaxf(__fsub_rn(rbx, ltx), 0.f);
            float h = fmaxf(__fsub_rn(rby, lty), 0.f);
            float inter = __fmul_rn(w, h);
            // ref order: ((area_i + area_j) - inter) + 1e-9
            float denom = __fadd_rn(__fsub_rn(__fadd_rn(rarea, ca[cc]), inter), 1e-9f);
            float iou = __fdiv_rn(inter, denom);
            if (iou > NMS_THR) {
                if (cc < 32) w0 |= 1u << cc; else w1 |= 1u << (cc - 32);
            }
        }
    }
    maskT[(blockIdx.x * 2 + 0) * 2048 + row] = w0;
    maskT[(blockIdx.x * 2 + 1) * 2048 + row] = w1;
}

// ---- greedy scan: word-parallel, transposed mask, 4-deep dwordx4 pipeline ----
__global__ __launch_bounds__(64) void k_final(
        const u32* __restrict__ maskT, const float* __restrict__ vals,
        const float* __restrict__ cand_bx, float* __restrict__ out) {
    int lane = threadIdx.x;  // lane owns keep/removed bits [lane*32, lane*32+32)
    const uint4* mt = (const uint4*)maskT + (size_t)lane * 512;  // column base
    const float4* vp = (const float4*)vals + (size_t)lane * 8;
    float4 vv[8];
#pragma unroll
    for (int j = 0; j < 8; j++) vv[j] = vp[j];
    uint4 P[4][8];
#pragma unroll
    for (int ww = 0; ww < 4; ww++)
#pragma unroll
        for (int j = 0; j < 8; j++) P[ww][j] = mt[ww * 8 + j];
    u32 validw = 0;
#pragma unroll
    for (int j = 0; j < 8; j++) {
        validw |= (vv[j].x > SCORE_THR ? 1u : 0u) << (4 * j + 0);
        validw |= (vv[j].y > SCORE_THR ? 1u : 0u) << (4 * j + 1);
        validw |= (vv[j].z > SCORE_THR ? 1u : 0u) << (4 * j + 2);
        validw |= (vv[j].w > SCORE_THR ? 1u : 0u) << (4 * j + 3);
    }
    u32 removed = 0, keepw = 0;
    for (int w4 = 0; w4 < 64; w4 += 4) {
#pragma unroll
        for (int s = 0; s < 4; s++) {
            int w = w4 + s;
            u32 rw[32];
#pragma unroll
            for (int j = 0; j < 8; j++) {
                rw[4 * j + 0] = P[s][j].x; rw[4 * j + 1] = P[s][j].y;
                rw[4 * j + 2] = P[s][j].z; rw[4 * j + 3] = P[s][j].w;
            }
            if (w + 4 < 64) {       // re-issue this slot for word w+4
#pragma unroll
                for (int j = 0; j < 8; j++) P[s][j] = mt[(w + 4) * 8 + j];
            }
            u32 alive = validw & ~removed;
#pragma unroll
            for (int j = 0; j < 32; j++)
                alive &= ((alive >> j) & 1u) ? ~rw[j] : 0xFFFFFFFFu;
            u32 kw = (u32)__shfl((int)alive, w);
            if (lane == w) keepw = kw;
            u32 acc = 0;
#pragma unroll
            for (int j = 0; j < 32; j++) acc |= ((kw >> j) & 1u) ? rw[j] : 0u;
            removed |= acc;
        }
    }
#pragma unroll
    for (int b = 0; b < 32; b++) {
        int i = lane * 32 + b;
        bool kp = (keepw >> b) & 1u;
        const float4 bx = ((const float4*)cand_bx)[i];
        float v = (b & 3) == 0 ? vv[b >> 2].x :
                  (b & 3) == 1 ? vv[b >> 2].y :
                  (b & 3) == 2 ? vv[b >> 2].z : vv[b >> 2].w;
        out[i * 5 + 0] = kp ? bx.x : 0.f;
        out[i * 5 + 1] = kp ? bx.y : 0.f;
        out[i * 5 + 2] = kp ? bx.z : 0.f;
        out[i * 5 + 3] = kp ? bx.w : 0.f;
        out[i * 5 + 4] = kp ? v : 0.f;
    }
}

extern "C" void kernel_launch(void* const* d_in, const int* in_sizes, int n_in,
                              void* d_out, int out_size, void* d_ws, size_t ws_size,
                              hipStream_t stream) {
    const float* boxes = (const float*)d_in[0];
    const float* scores = (const float*)d_in[1];
    const float* center = (const float*)d_in[2];
    float* out = (float*)d_out;
    int R = in_sizes[2];

    char* w = (char*)d_ws;
    u32* offs   = (u32*)(w + WS_OFFS);
    u32* binpos = (u32*)(w + WS_BINPOS);
    u32* hdr    = (u32*)(w + WS_HDR);
    float* cbx  = (float*)(w + WS_CBX);
    float* nbx  = (float*)(w + WS_NBX);
    float* vls  = (float*)(w + WS_VALS);
    u32* maskT  = (u32*)(w + WS_MASK);
    u32* hrep   = (u32*)(w + WS_HREP);  // aliases maskT[0:128K]  (dead after k_scan)
    u64* buf    = (u64*)(w + WS_BUF);   // aliases maskT[128K:160K] (dead before k_mask)

    // zero binpos+hdr+cand/nms/vals padding + hrep (ws poisoned 0xAA per call)
    hipMemsetAsync(w, 0, WS_BUF, stream);

    k_hist<<<256, 256, 0, stream>>>(scores, center, R, hrep);
    k_scan<<<1, 64, 0, stream>>>(hrep, offs, hdr);
    k_collect<<<256, 256, 0, stream>>>(scores, center, R, hdr, offs, binpos, buf);
    k_rank<<<1, 1024, 0, stream>>>(boxes, offs, hdr, buf, cbx, nbx, vls);
    k_mask<<<dim3(32, 32), 64, 0, stream>>>(nbx, maskT);
    k_final<<<1, 64, 0, stream>>>(maskT, vls, cbx, out);
}